// Round 12
// baseline (311.188 us; speedup 1.0000x reference)
//
#include <hip/hip_runtime.h>
#include <cmath>

#define NLEV 16
#define TSZ  (1u << 19)
#define TMASK (TSZ - 1u)
#define PR1 2654435761u
#define PR2 805459861u
#define NBUCK 32768          // 32^3 Morton buckets
#define TOTENT (16u << 19)   // total table entries (16 levels x 2^19)
#define NF 11                // staged levels 5..15

struct LvlP {
    float    rf[NLEV];
    unsigned s1[NLEV];
    unsigned s2[NLEV];
};

// ---------- helpers ----------
static __device__ __forceinline__ unsigned part1by2(unsigned x) {
    x &= 0x3FFu;
    x = (x | (x << 16)) & 0x030000FFu;
    x = (x | (x << 8))  & 0x0300F00Fu;
    x = (x | (x << 4))  & 0x030C30C3u;
    x = (x | (x << 2))  & 0x09249249u;
    return x;
}
static __device__ __forceinline__ unsigned bucket_of(float x0, float x1, float x2) {
    unsigned bx = min(31u, (unsigned)(x0 * 32.0f));
    unsigned by = min(31u, (unsigned)(x1 * 32.0f));
    unsigned bz = min(31u, (unsigned)(x2 * 32.0f));
    return part1by2(bx) | (part1by2(by) << 1) | (part1by2(bz) << 2);
}
static __device__ __forceinline__ unsigned short f2bf(float f) { // RNE
    unsigned u = __float_as_uint(f);
    unsigned r = ((u >> 16) & 1u) + 0x7FFFu;
    return (unsigned short)((u + r) >> 16);
}
static __device__ __forceinline__ float bf2f(unsigned short h) {
    return __uint_as_float(((unsigned)h) << 16);
}
static __device__ __forceinline__ unsigned packbf(float a, float b) {
    return (unsigned)f2bf(a) | ((unsigned)f2bf(b) << 16);
}

// ---------- table conversion (+ pos zeroing folded in) ----------
__global__ __launch_bounds__(256) void cvt_kernel(
    const float4* __restrict__ t4, uint4* __restrict__ tb4,
    unsigned* __restrict__ pos)
{
    unsigned i = blockIdx.x * 256 + threadIdx.x;     // quad of entries
    if (blockIdx.x < NBUCK / 256) pos[i] = 0u;       // fold zero_pos
    if (i >= TOTENT / 4) return;
    float4 a = t4[2 * i];
    float4 b = t4[2 * i + 1];
    uint4 o;
    o.x = packbf(a.x, a.y);
    o.y = packbf(a.z, a.w);
    o.z = packbf(b.x, b.y);
    o.w = packbf(b.z, b.w);
    tb4[i] = o;
}

// ---------- sort pipeline ----------
__global__ __launch_bounds__(256) void hist_kernel(
    const float* __restrict__ xs, unsigned* __restrict__ pos, int n)
{
    int i = blockIdx.x * 256 + threadIdx.x;
    if (i >= n) return;
    unsigned b = bucket_of(xs[3 * i], xs[3 * i + 1], xs[3 * i + 2]);
    atomicAdd(&pos[b], 1u);
}

__global__ __launch_bounds__(256) void scanA_kernel(
    unsigned* __restrict__ pos, unsigned* __restrict__ bsum)
{
    __shared__ unsigned sh[256];
    int t = threadIdx.x;
    int g = blockIdx.x * 256 + t;
    unsigned v = pos[g];
    sh[t] = v;
    __syncthreads();
    for (int off = 1; off < 256; off <<= 1) {
        unsigned u = (t >= off) ? sh[t - off] : 0u;
        __syncthreads();
        sh[t] += u;
        __syncthreads();
    }
    pos[g] = sh[t] - v;                 // block-exclusive
    if (t == 255) bsum[blockIdx.x] = sh[255];
}

__global__ __launch_bounds__(128) void scanB_kernel(unsigned* __restrict__ bsum)
{
    __shared__ unsigned sh[128];
    int t = threadIdx.x;
    unsigned v = bsum[t];
    sh[t] = v;
    __syncthreads();
    for (int off = 1; off < 128; off <<= 1) {
        unsigned u = (t >= off) ? sh[t - off] : 0u;
        __syncthreads();
        sh[t] += u;
        __syncthreads();
    }
    bsum[t] = sh[t] - v;                // exclusive block offsets
}

// scanC folded in: global position = block-exclusive atomic + bsum[block]
__global__ __launch_bounds__(256) void scatter_kernel(
    const float* __restrict__ xs, unsigned* __restrict__ pos,
    const unsigned* __restrict__ bsum, float4* __restrict__ S, int n)
{
    int i = blockIdx.x * 256 + threadIdx.x;
    if (i >= n) return;
    float x0 = xs[3 * i], x1 = xs[3 * i + 1], x2 = xs[3 * i + 2];
    unsigned b = bucket_of(x0, x1, x2);
    unsigned j = atomicAdd(&pos[b], 1u) + bsum[b >> 8];
    S[j] = make_float4(x0, x1, x2, __uint_as_float((unsigned)i));
}

// ---------- per-level encode core on bf16 table: 8B pair loads ----------
template <bool DENSE>
static __device__ __forceinline__ float2 enc_one_bf(
    float x0, float x1, float x2, float rf, unsigned st1, unsigned st2,
    unsigned lbase, const uint2* __restrict__ tb)
{
    float s0 = x0 * rf, s1f = x1 * rf, s2f = x2 * rf;
    float p0 = floorf(s0), p1 = floorf(s1f), p2 = floorf(s2f);
    float w0 = s0 - p0, w1 = s1f - p1, w2 = s2f - p2;
    unsigned c0 = (unsigned)p0, c1 = (unsigned)p1, c2 = (unsigned)p2;

    float2 f[8];
    #pragma unroll
    for (int p = 0; p < 4; ++p) {
        unsigned oy = (p >> 1) & 1u, oz = p & 1u;
        unsigned q0, q1;
        if (DENSE) {
            unsigned b = c0 + (c1 + oy) * st1 + (c2 + oz) * st2;
            q0 = b; q1 = b + 1u;
        } else {
            unsigned h = ((c1 + oy) * PR1) ^ ((c2 + oz) * PR2);
            q0 = (h ^ c0) & TMASK;
            q1 = (h ^ (c0 + 1u)) & TMASK;
        }
        uint2 v0 = tb[(lbase + (q0 & ~1u)) >> 1];
        unsigned ua = (q0 & 1u) ? v0.y : v0.x;
        bool one = DENSE ? ((q0 & 1u) == 0u) : ((c0 & 1u) == 0u);
        unsigned ub;
        if (one) {
            ub = (q0 & 1u) ? v0.x : v0.y;
        } else {
            uint2 v1 = tb[(lbase + (q1 & ~1u)) >> 1];
            ub = (q1 & 1u) ? v1.y : v1.x;
        }
        f[p]     = make_float2(__uint_as_float(ua << 16),
                               __uint_as_float(ua & 0xFFFF0000u));
        f[p + 4] = make_float2(__uint_as_float(ub << 16),
                               __uint_as_float(ub & 0xFFFF0000u));
    }

    float i0w = 1.f - w0, i1w = 1.f - w1, i2w = 1.f - w2;
    float acc0 = 0.f, acc1 = 0.f;
    #pragma unroll
    for (int k = 0; k < 8; ++k) {
        float wa = ((k >> 2) & 1) ? w0 : i0w;
        float wb = ((k >> 1) & 1) ? w1 : i1w;
        float wcv = (k & 1) ? w2 : i2w;
        float wk = (wa * wb) * wcv;
        acc0 = fmaf(wk, f[k].x, acc0);
        acc1 = fmaf(wk, f[k].y, acc1);
    }
    return make_float2(acc0, acc1);
}

// ---------- levels 5-15, level-major (L2 clustering preserved) --------------
// unit u: level l = u+5. u<2 -> dense indexing (levels 5,6), else hashed.
__global__ __launch_bounds__(256) void enc_mixed_kernel(
    const float4* __restrict__ S, const uint2* __restrict__ tb,
    ushort2* __restrict__ F, int n, int C, LvlP lp)
{
    int bid = blockIdx.x;
    int u = bid / C;                    // 0..10
    int l = u + 5;
    int j = (bid - u * C) * 256 + (int)threadIdx.x;
    if (j >= n) return;

    float4 s4 = S[j];
    float2 r;
    if (u < 2)
        r = enc_one_bf<true>(s4.x, s4.y, s4.z, lp.rf[l], lp.s1[l], lp.s2[l],
                             (unsigned)l << 19, tb);
    else
        r = enc_one_bf<false>(s4.x, s4.y, s4.z, lp.rf[l], 0u, 0u,
                              (unsigned)l << 19, tb);
    F[(size_t)u * n + j] = make_ushort2(f2bf(r.x), f2bf(r.y));
}

// ---------- finalize: dense 0-4 in-reg -> LDS park -> cooperative scatter ---
__global__ __launch_bounds__(256) void finalize_kernel(
    const float4* __restrict__ S, const uint2* __restrict__ tb,
    const ushort2* __restrict__ F, float4* __restrict__ out4, int n, LvlP lp)
{
    __shared__ ushort2 tile[NLEV][257];
    __shared__ unsigned sorig[256];
    int tid = threadIdx.x;
    int base = blockIdx.x * 256;
    int j = base + tid;

    if (j < n) {
        float4 s4 = S[j];
        sorig[tid] = __float_as_uint(s4.w);
        #pragma unroll
        for (int l = 0; l < 5; ++l) {
            float2 r = enc_one_bf<true>(s4.x, s4.y, s4.z, lp.rf[l], lp.s1[l], lp.s2[l],
                                        (unsigned)l << 19, tb);
            tile[l][tid] = make_ushort2(f2bf(r.x), f2bf(r.y));
        }
        #pragma unroll
        for (int u = 0; u < NF; ++u)
            tile[5 + u][tid] = F[(size_t)u * n + j];
    }
    __syncthreads();

    int nblk = min(256, n - base);
    #pragma unroll
    for (int r = 0; r < 8; ++r) {
        int idx = tid + 256 * r;       // 256 pts x 8 quads
        int pp = idx >> 3;
        int q  = idx & 7;
        if (pp < nblk) {
            ushort2 a = tile[2 * q][pp];
            ushort2 b = tile[2 * q + 1][pp];
            out4[(size_t)sorig[pp] * 8 + q] =
                make_float4(bf2f(a.x), bf2f(a.y), bf2f(b.x), bf2f(b.y));
        }
    }
}

// ---------- fallback: point-major, unsorted, fp32 table ----------
__global__ __launch_bounds__(256) void hashenc_kernel(
    const float* __restrict__ xs, const float* __restrict__ table,
    float* __restrict__ out, int n, LvlP lp)
{
    int i = blockIdx.x * 256 + threadIdx.x;
    if (i >= n) return;
    float x0 = xs[3 * i], x1 = xs[3 * i + 1], x2 = xs[3 * i + 2];
    const float2* __restrict__ t2 = (const float2*)table;
    float2* __restrict__ o2 = (float2*)out;
    #pragma unroll
    for (int l = 0; l < NLEV; ++l) {
        float rf = lp.rf[l];
        float s0 = x0 * rf, s1f = x1 * rf, s2f = x2 * rf;
        float p0 = floorf(s0), p1 = floorf(s1f), p2 = floorf(s2f);
        float w0 = s0 - p0, w1 = s1f - p1, w2 = s2f - p2;
        unsigned c0 = (unsigned)p0, c1 = (unsigned)p1, c2 = (unsigned)p2;
        float2 f[8];
        #pragma unroll
        for (int k = 0; k < 8; ++k) {
            unsigned a0 = c0 + ((k >> 2) & 1u), a1 = c1 + ((k >> 1) & 1u), a2 = c2 + (k & 1u);
            unsigned id;
            if (l < 7) id = a0 + a1 * lp.s1[l] + a2 * lp.s2[l];
            else       id = (a0 ^ (a1 * PR1) ^ (a2 * PR2)) & TMASK;
            f[k] = t2[((unsigned)l << 19) + id];
        }
        float i0 = 1.f - w0, i1 = 1.f - w1, i2 = 1.f - w2;
        float acc0 = 0.f, acc1 = 0.f;
        #pragma unroll
        for (int k = 0; k < 8; ++k) {
            float wa = ((k >> 2) & 1) ? w0 : i0;
            float wb = ((k >> 1) & 1) ? w1 : i1;
            float wcv = (k & 1) ? w2 : i2;
            float wk = (wa * wb) * wcv;
            acc0 = fmaf(wk, f[k].x, acc0);
            acc1 = fmaf(wk, f[k].y, acc1);
        }
        o2[(size_t)i * 16 + l] = make_float2(acc0, acc1);
    }
}

extern "C" void kernel_launch(void* const* d_in, const int* in_sizes, int n_in,
                              void* d_out, int out_size, void* d_ws, size_t ws_size,
                              hipStream_t stream)
{
    const float* xs    = (const float*)d_in[0];
    const float* table = (const float*)d_in[1];
    float* out = (float*)d_out;
    int n = in_sizes[0] / 3;

    // Replicate numpy's resolution computation exactly (same libm, same machine)
    LvlP lp;
    double B = exp((log(512.0) - log(16.0)) / 15.0);
    for (int l = 0; l < NLEV; ++l) {
        double rd;
        if (l == 0)      rd = 16.0;
        else if (l == 1) rd = floor(16.0 * B);
        else if (l == 2) rd = floor(16.0 * (B * B));
        else             rd = floor(16.0 * pow(B, (double)l));
        unsigned r = (unsigned)rd;
        lp.rf[l] = (float)r;
        lp.s1[l] = r + 1u;
        lp.s2[l] = (r + 1u) * (r + 1u);
    }

    int C = (n + 255) / 256;
    size_t posB  = (size_t)NBUCK * 4;               // 128 KB
    size_t bsumB = 1024;
    size_t sB    = (size_t)n * 16;                  // sorted {x,y,z,orig}
    size_t fB    = (size_t)NF * (size_t)n * 4;      // bf16x2, levels 5..15
    size_t tbB   = (size_t)TOTENT * 4;              // packed bf16 table, 33.5 MB
    size_t need  = posB + bsumB + sB + fB + tbB;    // ~94 MB

    if (ws_size >= need) {
        char* wsc = (char*)d_ws;
        unsigned* pos  = (unsigned*)wsc;
        unsigned* bsum = (unsigned*)(wsc + posB);
        float4*   S    = (float4*)(wsc + posB + bsumB);
        ushort2*  F    = (ushort2*)(wsc + posB + bsumB + sB);
        uint2*    tb   = (uint2*)(wsc + posB + bsumB + sB + fB);

        cvt_kernel<<<TOTENT / 4 / 256, 256, 0, stream>>>(
            (const float4*)table, (uint4*)tb, pos);
        hist_kernel<<<C, 256, 0, stream>>>(xs, pos, n);
        scanA_kernel<<<NBUCK / 256, 256, 0, stream>>>(pos, bsum);
        scanB_kernel<<<1, 128, 0, stream>>>(bsum);
        scatter_kernel<<<C, 256, 0, stream>>>(xs, pos, bsum, S, n);
        enc_mixed_kernel<<<NF * C, 256, 0, stream>>>(S, tb, F, n, C, lp);
        finalize_kernel<<<C, 256, 0, stream>>>(S, tb, F, (float4*)out, n, lp);
    } else {
        hashenc_kernel<<<C, 256, 0, stream>>>(xs, table, out, n, lp);
    }
}

// Round 14
// 298.270 us; speedup vs baseline: 1.0433x; 1.0433x over previous
//
#include <hip/hip_runtime.h>
#include <cmath>

#define NLEV 16
#define TSZ  (1u << 19)
#define TMASK (TSZ - 1u)
#define PR1 2654435761u
#define PR2 805459861u
#define NBUCK 32768          // 32^3 Morton buckets
#define TOTENT (16u << 19)   // total table entries (16 levels x 2^19)
#define NF 9                 // staged hashed levels 7..15

typedef float floatx4 __attribute__((ext_vector_type(4)));

struct LvlP {
    float    rf[NLEV];
    unsigned s1[NLEV];
    unsigned s2[NLEV];
};

// ---------- helpers ----------
static __device__ __forceinline__ unsigned part1by2(unsigned x) {
    x &= 0x3FFu;
    x = (x | (x << 16)) & 0x030000FFu;
    x = (x | (x << 8))  & 0x0300F00Fu;
    x = (x | (x << 4))  & 0x030C30C3u;
    x = (x | (x << 2))  & 0x09249249u;
    return x;
}
static __device__ __forceinline__ unsigned bucket_of(float x0, float x1, float x2) {
    unsigned bx = min(31u, (unsigned)(x0 * 32.0f));
    unsigned by = min(31u, (unsigned)(x1 * 32.0f));
    unsigned bz = min(31u, (unsigned)(x2 * 32.0f));
    return part1by2(bx) | (part1by2(by) << 1) | (part1by2(bz) << 2);
}
static __device__ __forceinline__ unsigned short f2bf(float f) { // RNE
    unsigned u = __float_as_uint(f);
    unsigned r = ((u >> 16) & 1u) + 0x7FFFu;
    return (unsigned short)((u + r) >> 16);
}
static __device__ __forceinline__ float bf2f(unsigned short h) {
    return __uint_as_float(((unsigned)h) << 16);
}
static __device__ __forceinline__ unsigned packbf(float a, float b) {
    return (unsigned)f2bf(a) | ((unsigned)f2bf(b) << 16);
}

// ---------- table conversion (+ pos zeroing folded in) ----------
__global__ __launch_bounds__(256) void cvt_kernel(
    const float4* __restrict__ t4, uint4* __restrict__ tb4,
    unsigned* __restrict__ pos)
{
    unsigned i = blockIdx.x * 256 + threadIdx.x;     // quad of entries
    if (blockIdx.x < NBUCK / 256) pos[i] = 0u;       // fold zero_pos
    if (i >= TOTENT / 4) return;
    float4 a = t4[2 * i];
    float4 b = t4[2 * i + 1];
    uint4 o;
    o.x = packbf(a.x, a.y);
    o.y = packbf(a.z, a.w);
    o.z = packbf(b.x, b.y);
    o.w = packbf(b.z, b.w);
    tb4[i] = o;
}

// ---------- sort pipeline ----------
__global__ __launch_bounds__(256) void hist_kernel(
    const float* __restrict__ xs, unsigned* __restrict__ pos, int n)
{
    int i = blockIdx.x * 256 + threadIdx.x;
    if (i >= n) return;
    unsigned b = bucket_of(xs[3 * i], xs[3 * i + 1], xs[3 * i + 2]);
    atomicAdd(&pos[b], 1u);
}

__global__ __launch_bounds__(256) void scanA_kernel(
    unsigned* __restrict__ pos, unsigned* __restrict__ bsum)
{
    __shared__ unsigned sh[256];
    int t = threadIdx.x;
    int g = blockIdx.x * 256 + t;
    unsigned v = pos[g];
    sh[t] = v;
    __syncthreads();
    for (int off = 1; off < 256; off <<= 1) {
        unsigned u = (t >= off) ? sh[t - off] : 0u;
        __syncthreads();
        sh[t] += u;
        __syncthreads();
    }
    pos[g] = sh[t] - v;                 // block-exclusive
    if (t == 255) bsum[blockIdx.x] = sh[255];
}

__global__ __launch_bounds__(128) void scanB_kernel(unsigned* __restrict__ bsum)
{
    __shared__ unsigned sh[128];
    int t = threadIdx.x;
    unsigned v = bsum[t];
    sh[t] = v;
    __syncthreads();
    for (int off = 1; off < 128; off <<= 1) {
        unsigned u = (t >= off) ? sh[t - off] : 0u;
        __syncthreads();
        sh[t] += u;
        __syncthreads();
    }
    bsum[t] = sh[t] - v;                // exclusive block offsets
}

// scanC folded in: global position = block-exclusive atomic + bsum[block]
__global__ __launch_bounds__(256) void scatter_kernel(
    const float* __restrict__ xs, unsigned* __restrict__ pos,
    const unsigned* __restrict__ bsum, float4* __restrict__ S, int n)
{
    int i = blockIdx.x * 256 + threadIdx.x;
    if (i >= n) return;
    float x0 = xs[3 * i], x1 = xs[3 * i + 1], x2 = xs[3 * i + 2];
    unsigned b = bucket_of(x0, x1, x2);
    unsigned j = atomicAdd(&pos[b], 1u) + bsum[b >> 8];
    S[j] = make_float4(x0, x1, x2, __uint_as_float((unsigned)i));
}

// ---------- per-level encode core on bf16 table: 8B pair loads ----------
template <bool DENSE>
static __device__ __forceinline__ float2 enc_one_bf(
    float x0, float x1, float x2, float rf, unsigned st1, unsigned st2,
    unsigned lbase, const uint2* __restrict__ tb)
{
    float s0 = x0 * rf, s1f = x1 * rf, s2f = x2 * rf;
    float p0 = floorf(s0), p1 = floorf(s1f), p2 = floorf(s2f);
    float w0 = s0 - p0, w1 = s1f - p1, w2 = s2f - p2;
    unsigned c0 = (unsigned)p0, c1 = (unsigned)p1, c2 = (unsigned)p2;

    float2 f[8];
    #pragma unroll
    for (int p = 0; p < 4; ++p) {
        unsigned oy = (p >> 1) & 1u, oz = p & 1u;
        unsigned q0, q1;
        if (DENSE) {
            unsigned b = c0 + (c1 + oy) * st1 + (c2 + oz) * st2;
            q0 = b; q1 = b + 1u;
        } else {
            unsigned h = ((c1 + oy) * PR1) ^ ((c2 + oz) * PR2);
            q0 = (h ^ c0) & TMASK;
            q1 = (h ^ (c0 + 1u)) & TMASK;
        }
        uint2 v0 = tb[(lbase + (q0 & ~1u)) >> 1];
        unsigned ua = (q0 & 1u) ? v0.y : v0.x;
        bool one = DENSE ? ((q0 & 1u) == 0u) : ((c0 & 1u) == 0u);
        unsigned ub;
        if (one) {
            ub = (q0 & 1u) ? v0.x : v0.y;
        } else {
            uint2 v1 = tb[(lbase + (q1 & ~1u)) >> 1];
            ub = (q1 & 1u) ? v1.y : v1.x;
        }
        f[p]     = make_float2(__uint_as_float(ua << 16),
                               __uint_as_float(ua & 0xFFFF0000u));
        f[p + 4] = make_float2(__uint_as_float(ub << 16),
                               __uint_as_float(ub & 0xFFFF0000u));
    }

    float i0w = 1.f - w0, i1w = 1.f - w1, i2w = 1.f - w2;
    float acc0 = 0.f, acc1 = 0.f;
    #pragma unroll
    for (int k = 0; k < 8; ++k) {
        float wa = ((k >> 2) & 1) ? w0 : i0w;
        float wb = ((k >> 1) & 1) ? w1 : i1w;
        float wcv = (k & 1) ? w2 : i2w;
        float wk = (wa * wb) * wcv;
        acc0 = fmaf(wk, f[k].x, acc0);
        acc1 = fmaf(wk, f[k].y, acc1);
    }
    return make_float2(acc0, acc1);
}

// ---------- hashed levels 7-15, level-major (L2 clustering preserved) -------
__global__ __launch_bounds__(256) void enc_hashed_kernel(
    const float4* __restrict__ S, const uint2* __restrict__ tb,
    ushort2* __restrict__ F, int n, int C, LvlP lp)
{
    int bid = blockIdx.x;
    int u = bid / C;                    // 0..8
    int l = u + 7;
    int j = (bid - u * C) * 256 + (int)threadIdx.x;
    if (j >= n) return;

    float4 s4 = S[j];
    float2 r = enc_one_bf<false>(s4.x, s4.y, s4.z, lp.rf[l], 0u, 0u,
                                 (unsigned)l << 19, tb);
    F[(size_t)u * n + j] = make_ushort2(f2bf(r.x), f2bf(r.y));
}

// ---------- finalize: dense 0-6 in-reg -> LDS park -> cooperative nt-scatter
__global__ __launch_bounds__(256) void finalize_kernel(
    const float4* __restrict__ S, const uint2* __restrict__ tb,
    const ushort2* __restrict__ F, float* __restrict__ out, int n, LvlP lp)
{
    __shared__ ushort2 tile[NLEV][257];
    __shared__ unsigned sorig[256];
    int tid = threadIdx.x;
    int base = blockIdx.x * 256;
    int j = base + tid;

    if (j < n) {
        float4 s4 = S[j];
        sorig[tid] = __float_as_uint(s4.w);
        #pragma unroll
        for (int l = 0; l < 7; ++l) {
            float2 r = enc_one_bf<true>(s4.x, s4.y, s4.z, lp.rf[l], lp.s1[l], lp.s2[l],
                                        (unsigned)l << 19, tb);
            tile[l][tid] = make_ushort2(f2bf(r.x), f2bf(r.y));
        }
        #pragma unroll
        for (int u = 0; u < NF; ++u)
            tile[7 + u][tid] = F[(size_t)u * n + j];
    }
    __syncthreads();

    floatx4* __restrict__ out4 = (floatx4*)out;
    int nblk = min(256, n - base);
    #pragma unroll
    for (int r = 0; r < 8; ++r) {
        int idx = tid + 256 * r;       // 256 pts x 8 quads
        int pp = idx >> 3;
        int q  = idx & 7;
        if (pp < nblk) {
            ushort2 a = tile[2 * q][pp];
            ushort2 b = tile[2 * q + 1][pp];
            floatx4 v = { bf2f(a.x), bf2f(a.y), bf2f(b.x), bf2f(b.y) };
            // out is write-only for us: nt store bypasses L2 write-allocate
            __builtin_nontemporal_store(v, &out4[(size_t)sorig[pp] * 8 + q]);
        }
    }
}

// ---------- fallback: point-major, unsorted, fp32 table ----------
__global__ __launch_bounds__(256) void hashenc_kernel(
    const float* __restrict__ xs, const float* __restrict__ table,
    float* __restrict__ out, int n, LvlP lp)
{
    int i = blockIdx.x * 256 + threadIdx.x;
    if (i >= n) return;
    float x0 = xs[3 * i], x1 = xs[3 * i + 1], x2 = xs[3 * i + 2];
    const float2* __restrict__ t2 = (const float2*)table;
    float2* __restrict__ o2 = (float2*)out;
    #pragma unroll
    for (int l = 0; l < NLEV; ++l) {
        float rf = lp.rf[l];
        float s0 = x0 * rf, s1f = x1 * rf, s2f = x2 * rf;
        float p0 = floorf(s0), p1 = floorf(s1f), p2 = floorf(s2f);
        float w0 = s0 - p0, w1 = s1f - p1, w2 = s2f - p2;
        unsigned c0 = (unsigned)p0, c1 = (unsigned)p1, c2 = (unsigned)p2;
        float2 f[8];
        #pragma unroll
        for (int k = 0; k < 8; ++k) {
            unsigned a0 = c0 + ((k >> 2) & 1u), a1 = c1 + ((k >> 1) & 1u), a2 = c2 + (k & 1u);
            unsigned id;
            if (l < 7) id = a0 + a1 * lp.s1[l] + a2 * lp.s2[l];
            else       id = (a0 ^ (a1 * PR1) ^ (a2 * PR2)) & TMASK;
            f[k] = t2[((unsigned)l << 19) + id];
        }
        float i0 = 1.f - w0, i1 = 1.f - w1, i2 = 1.f - w2;
        float acc0 = 0.f, acc1 = 0.f;
        #pragma unroll
        for (int k = 0; k < 8; ++k) {
            float wa = ((k >> 2) & 1) ? w0 : i0;
            float wb = ((k >> 1) & 1) ? w1 : i1;
            float wcv = (k & 1) ? w2 : i2;
            float wk = (wa * wb) * wcv;
            acc0 = fmaf(wk, f[k].x, acc0);
            acc1 = fmaf(wk, f[k].y, acc1);
        }
        o2[(size_t)i * 16 + l] = make_float2(acc0, acc1);
    }
}

extern "C" void kernel_launch(void* const* d_in, const int* in_sizes, int n_in,
                              void* d_out, int out_size, void* d_ws, size_t ws_size,
                              hipStream_t stream)
{
    const float* xs    = (const float*)d_in[0];
    const float* table = (const float*)d_in[1];
    float* out = (float*)d_out;
    int n = in_sizes[0] / 3;

    // Replicate numpy's resolution computation exactly (same libm, same machine)
    LvlP lp;
    double B = exp((log(512.0) - log(16.0)) / 15.0);
    for (int l = 0; l < NLEV; ++l) {
        double rd;
        if (l == 0)      rd = 16.0;
        else if (l == 1) rd = floor(16.0 * B);
        else if (l == 2) rd = floor(16.0 * (B * B));
        else             rd = floor(16.0 * pow(B, (double)l));
        unsigned r = (unsigned)rd;
        lp.rf[l] = (float)r;
        lp.s1[l] = r + 1u;
        lp.s2[l] = (r + 1u) * (r + 1u);
    }

    int C = (n + 255) / 256;
    size_t posB  = (size_t)NBUCK * 4;               // 128 KB
    size_t bsumB = 1024;
    size_t sB    = (size_t)n * 16;                  // sorted {x,y,z,orig}
    size_t fB    = (size_t)NF * (size_t)n * 4;      // bf16x2, hashed levels
    size_t tbB   = (size_t)TOTENT * 4;              // packed bf16 table, 33.5 MB
    size_t need  = posB + bsumB + sB + fB + tbB;    // ~86 MB

    if (ws_size >= need) {
        char* wsc = (char*)d_ws;
        unsigned* pos  = (unsigned*)wsc;
        unsigned* bsum = (unsigned*)(wsc + posB);
        float4*   S    = (float4*)(wsc + posB + bsumB);
        ushort2*  F    = (ushort2*)(wsc + posB + bsumB + sB);
        uint2*    tb   = (uint2*)(wsc + posB + bsumB + sB + fB);

        cvt_kernel<<<TOTENT / 4 / 256, 256, 0, stream>>>(
            (const float4*)table, (uint4*)tb, pos);
        hist_kernel<<<C, 256, 0, stream>>>(xs, pos, n);
        scanA_kernel<<<NBUCK / 256, 256, 0, stream>>>(pos, bsum);
        scanB_kernel<<<1, 128, 0, stream>>>(bsum);
        scatter_kernel<<<C, 256, 0, stream>>>(xs, pos, bsum, S, n);
        enc_hashed_kernel<<<NF * C, 256, 0, stream>>>(S, tb, F, n, C, lp);
        finalize_kernel<<<C, 256, 0, stream>>>(S, tb, F, out, n, lp);
    } else {
        hashenc_kernel<<<C, 256, 0, stream>>>(xs, table, out, n, lp);
    }
}